// Round 7
// baseline (230.785 us; speedup 1.0000x reference)
//
#include <hip/hip_runtime.h>
#include <math.h>

#define FFT_N 512
#define WAVES_PER_BLOCK 4
#define CH_STRIDE 576   // per-chain LDS region in float2; max addr used = 574

// Compile-time-only fence: orders the C++ LDS accesses (memory clobber) and
// pins machine-scheduler motion (wave_barrier) — emits ZERO instructions.
// Correctness: each wave owns its LDS regions, and same-wave DS operations
// are processed IN ORDER by hardware, so write->read needs no s_waitcnt;
// the compiler inserts counted lgkmcnt(N) before register USES only.
#define WAVE_LDS_FENCE() do { \
    asm volatile("" ::: "memory"); \
    __builtin_amdgcn_wave_barrier(); \
    asm volatile("" ::: "memory"); \
} while (0)

// In-register 8-point complex DFT (DIF radix-2^3), outputs in NATURAL order.
__device__ __forceinline__ void fft8(float* re, float* im) {
    const float C = 0.70710678118654752440f;
    float tr[8], ti[8];
    tr[0]=re[0]+re[4]; ti[0]=im[0]+im[4];
    tr[4]=re[0]-re[4]; ti[4]=im[0]-im[4];
    tr[1]=re[1]+re[5]; ti[1]=im[1]+im[5];
    tr[5]=re[1]-re[5]; ti[5]=im[1]-im[5];
    tr[2]=re[2]+re[6]; ti[2]=im[2]+im[6];
    tr[6]=re[2]-re[6]; ti[6]=im[2]-im[6];
    tr[3]=re[3]+re[7]; ti[3]=im[3]+im[7];
    tr[7]=re[3]-re[7]; ti[7]=im[3]-im[7];
    { float a=tr[5], b=ti[5]; tr[5]=C*(a+b); ti[5]=C*(b-a); }
    { float a=tr[6], b=ti[6]; tr[6]=b;       ti[6]=-a;      }
    { float a=tr[7], b=ti[7]; tr[7]=C*(b-a); ti[7]=-C*(a+b);}
    {
        float s0r=tr[0]+tr[2], s0i=ti[0]+ti[2];
        float s2r=tr[0]-tr[2], s2i=ti[0]-ti[2];
        float s1r=tr[1]+tr[3], s1i=ti[1]+ti[3];
        float dr =tr[1]-tr[3], di =ti[1]-ti[3];
        float s3r= di, s3i=-dr;
        re[0]=s0r+s1r; im[0]=s0i+s1i;
        re[2]=s2r+s3r; im[2]=s2i+s3i;
        re[4]=s0r-s1r; im[4]=s0i-s1i;
        re[6]=s2r-s3r; im[6]=s2i-s3i;
    }
    {
        float s0r=tr[4]+tr[6], s0i=ti[4]+ti[6];
        float s2r=tr[4]-tr[6], s2i=ti[4]-ti[6];
        float s1r=tr[5]+tr[7], s1i=ti[5]+ti[7];
        float dr =tr[5]-tr[7], di =ti[5]-ti[7];
        float s3r= di, s3i=-dr;
        re[1]=s0r+s1r; im[1]=s0i+s1i;
        re[3]=s2r+s3r; im[3]=s2i+s3i;
        re[5]=s0r-s1r; im[5]=s0i-s1i;
        re[7]=s2r-s3r; im[7]=s2i-s3i;
    }
}

// Apply tw[k] = base^k (chained complex multiply) to regs 1..7.
__device__ __forceinline__ void twiddle_chain(float* re, float* im,
                                              float c, float s) {
    float cr = c, ci = s;
#pragma unroll
    for (int k = 1; k < 8; ++k) {
        float a = re[k], b = im[k];
        re[k] = a * cr - b * ci;
        im[k] = a * ci + b * cr;
        float ncr = cr * c - ci * s;
        float nci = cr * s + ci * c;
        cr = ncr; ci = nci;
    }
}

// Exchange-3 slot swizzle: A3(k) = 64*(k>>6) + swz3(k&63).
// swz3 bank-pair bits: [m0^m2, m3, m4, m5]; high bits [m1, m2].
// Injective in m-bits{0,3,4,5} (write via rot3(lane)) and in
// m-bits{2,3,4,5} (both mirrored reads) within every 16-lane phase.
__device__ __forceinline__ int swz3(int m) {
    return ((m ^ (m >> 2)) & 1)
         | (((m >> 3) & 7) << 1)
         | (((m >> 1) & 1) << 4)
         | (((m >> 2) & 1) << 5);
}

// One wave processes TWO row-pairs CONCURRENTLY as two explicitly named
// independent FFT chains (A and B) with disjoint LDS regions and shared
// fences. When chain A stalls on an LDS read return, chain B's VALU work
// issues — halving exposed stall time per pair and doubling in-flight
// global loads. Straight-line duplicated bodies: no pointer arrays, no
// chain-indexed register state (avoids any scratch-allocation risk).
// Per chain: z = x[2q] + i*x[2q+1], one 512-pt complex FFT,
// unpack Re(A) = (ReZ[k]+ReZ[N-k])/2, Re(B) = (ImZ[k]+ImZ[N-k])/2.
// Decimation: n = 64*n1 + 8*n2 + n3 ; k = k1 + 8*k2 + 64*k3.
// All LDS exchanges conflict-free under the 16-lane b64 phase model.
__global__ __launch_bounds__(256) void fft512_pack2_kernel(
        const float* __restrict__ x,
        const float* __restrict__ win,
        float* __restrict__ out) {
    __shared__ float2 lds[WAVES_PER_BLOCK * 2 * CH_STRIDE];

    const int wave = threadIdx.x >> 6;
    const int lane = threadIdx.x & 63;
    float2* __restrict__ LA = lds + wave * (2 * CH_STRIDE);
    float2* __restrict__ LB = LA + CH_STRIDE;

    const int t4   = lane << 2;
    const int u    = lane & 15;
    const int pp   = lane >> 4;
    const int x0sw = (lane >> 2) & 3;            // exch-0 write XOR (on j)
    const int l0r  = lane ^ pp;                  // exch-0 read lane index
    const int k1p  = lane >> 3;                  // exch-1 read / exch-2 write role
    const int n3p  = lane & 7;
    const int rl   = (lane >> 3) | ((lane & 7) << 3);  // post-C k&63
    const int s3w  = swz3(rl);                   // exch-3 write slot

    int sm[4], smm[4];
#pragma unroll
    for (int j = 0; j < 4; ++j) {
        const int m = 4 * u + j;
        sm[j]  = swz3(m);
        smm[j] = swz3((64 - m) & 63);
    }

    // Twiddle bases (lane-only) — shared by both chains.
    float cA, sA, cB, sB;
    __sincosf(-6.283185307179586f * (float)lane * (1.0f / 512.0f), &sA, &cA);
    __sincosf(-6.283185307179586f * (float)n3p  * (1.0f / 64.0f),  &sB, &cB);

    const int pair0 = (blockIdx.x * WAVES_PER_BLOCK + wave) * 2;

    const float4 w0 = *(const float4*)(win + t4);
    const float4 w1 = *(const float4*)(win + t4 + 256);

    // ---- Global loads for BOTH chains: 8 KB/wave in flight ----
    const float* __restrict__ xpA = x + (size_t)(2 * pair0) * FFT_N;
    const float* __restrict__ xpB = xpA + 2 * FFT_N;
    const float4 Aa0 = *(const float4*)(xpA + t4);
    const float4 Ab0 = *(const float4*)(xpA + FFT_N + t4);
    const float4 Aa1 = *(const float4*)(xpA + t4 + 256);
    const float4 Ab1 = *(const float4*)(xpA + FFT_N + t4 + 256);
    const float4 Ba0 = *(const float4*)(xpB + t4);
    const float4 Bb0 = *(const float4*)(xpB + FFT_N + t4);
    const float4 Ba1 = *(const float4*)(xpB + t4 + 256);
    const float4 Bb1 = *(const float4*)(xpB + FFT_N + t4 + 256);

    // ---- Exchange 0 write: A0(i) = i ^ ((i>>4)&3) = base + (j^x0sw) ----
    {
        const float* a0 = (const float*)&Aa0;  const float* b0 = (const float*)&Ab0;
        const float* a1 = (const float*)&Aa1;  const float* b1 = (const float*)&Ab1;
        const float* c0 = (const float*)&Ba0;  const float* d0 = (const float*)&Bb0;
        const float* c1 = (const float*)&Ba1;  const float* d1 = (const float*)&Bb1;
        const float* W0 = (const float*)&w0;   const float* W1 = (const float*)&w1;
#pragma unroll
        for (int j = 0; j < 4; ++j) {
            const int sl = j ^ x0sw;
            LA[t4 +       sl] = make_float2(a0[j] * W0[j], b0[j] * W0[j]);
            LA[t4 + 256 + sl] = make_float2(a1[j] * W1[j], b1[j] * W1[j]);
            LB[t4 +       sl] = make_float2(c0[j] * W0[j], d0[j] * W0[j]);
            LB[t4 + 256 + sl] = make_float2(c1[j] * W1[j], d1[j] * W1[j]);
        }
    }
    WAVE_LDS_FENCE();

    // ---- Exchange 0 read: element 64*n1 + lane is at 64*n1 + (lane^pp) ----
    float reA[8], imA[8], reB[8], imB[8];
#pragma unroll
    for (int n1 = 0; n1 < 8; ++n1) {
        float2 va = LA[n1 * 64 + l0r];
        float2 vb = LB[n1 * 64 + l0r];
        reA[n1] = va.x; imA[n1] = va.y;
        reB[n1] = vb.x; imB[n1] = vb.y;
    }
    WAVE_LDS_FENCE();

    // ---- Stage A: DFT8 over n1 + twiddle W512^{lane*k1} ----
    fft8(reA, imA);
    fft8(reB, imB);
    twiddle_chain(reA, imA, cA, sA);
    twiddle_chain(reB, imB, cA, sA);

    // ---- Exchange 1: addr = k1*72 + (8*n2 + n3) ----
#pragma unroll
    for (int k1 = 0; k1 < 8; ++k1) {
        LA[k1 * 72 + lane] = make_float2(reA[k1], imA[k1]);
        LB[k1 * 72 + lane] = make_float2(reB[k1], imB[k1]);
    }
    WAVE_LDS_FENCE();
#pragma unroll
    for (int n2 = 0; n2 < 8; ++n2) {
        float2 va = LA[k1p * 72 + n2 * 8 + n3p];
        float2 vb = LB[k1p * 72 + n2 * 8 + n3p];
        reA[n2] = va.x; imA[n2] = va.y;
        reB[n2] = vb.x; imB[n2] = vb.y;
    }
    WAVE_LDS_FENCE();

    // ---- Stage B: DFT8 over n2 + twiddle W64^{n3p*k2} ----
    fft8(reA, imA);
    fft8(reB, imB);
    twiddle_chain(reA, imA, cB, sB);
    twiddle_chain(reB, imB, cB, sB);

    // ---- Exchange 2: addr = (k1*8 + k2)*9 + n3 ----
#pragma unroll
    for (int k2 = 0; k2 < 8; ++k2) {
        LA[(k1p * 8 + k2) * 9 + n3p] = make_float2(reA[k2], imA[k2]);
        LB[(k1p * 8 + k2) * 9 + n3p] = make_float2(reB[k2], imB[k2]);
    }
    WAVE_LDS_FENCE();
    // Read role: k1 = lane>>3, k2 = lane&7  =>  addr = lane*9 + n3.
#pragma unroll
    for (int n3 = 0; n3 < 8; ++n3) {
        float2 va = LA[lane * 9 + n3];
        float2 vb = LB[lane * 9 + n3];
        reA[n3] = va.x; imA[n3] = va.y;
        reB[n3] = vb.x; imB[n3] = vb.y;
    }
    WAVE_LDS_FENCE();

    // ---- Stage C ----
    fft8(reA, imA);
    fft8(reB, imB);
    // Thread holds Z[k], k = rl + 64*k3 (per chain).

    // ---- Exchange 3: Z[k] at 64*(k>>6) + swz3(k&63) ----
#pragma unroll
    for (int k3 = 0; k3 < 8; ++k3) {
        LA[(k3 << 6) + s3w] = make_float2(reA[k3], imA[k3]);
        LB[(k3 << 6) + s3w] = make_float2(reB[k3], imB[k3]);
    }
    WAVE_LDS_FENCE();

    // ---- Output: float4 stores, both chains ----
    float* __restrict__ oA0 = out + (size_t)(2 * pair0) * FFT_N;
    float* __restrict__ oA1 = oA0 + FFT_N;
    float* __restrict__ oB0 = oA0 + 2 * FFT_N;
    float* __restrict__ oB1 = oB0 + FFT_N;
#pragma unroll
    for (int half = 0; half < 2; ++half) {
        const int hk = 4 * half + pp;
        float4 raA, rbA, raB, rbB;
        float* paA = (float*)&raA;  float* pbA = (float*)&rbA;
        float* paB = (float*)&raB;  float* pbB = (float*)&rbB;
#pragma unroll
        for (int j = 0; j < 4; ++j) {
            const int m  = 4 * u + j;
            const int hn = ((512 - (hk << 6) - m) >> 6) & 7;
            const float2 zkA = LA[(hk << 6) + sm[j]];
            const float2 znA = LA[(hn << 6) + smm[j]];
            const float2 zkB = LB[(hk << 6) + sm[j]];
            const float2 znB = LB[(hn << 6) + smm[j]];
            paA[j] = 0.5f * (zkA.x + znA.x);
            pbA[j] = 0.5f * (zkA.y + znA.y);
            paB[j] = 0.5f * (zkB.x + znB.x);
            pbB[j] = 0.5f * (zkB.y + znB.y);
        }
        *(float4*)(oA0 + 256 * half + t4) = raA;
        *(float4*)(oA1 + 256 * half + t4) = rbA;
        *(float4*)(oB0 + 256 * half + t4) = raB;
        *(float4*)(oB1 + 256 * half + t4) = rbB;
    }
}

extern "C" void kernel_launch(void* const* d_in, const int* in_sizes, int n_in,
                              void* d_out, int out_size, void* d_ws, size_t ws_size,
                              hipStream_t stream) {
    const float* x   = (const float*)d_in[0];
    const float* win = (const float*)d_in[1];
    float* out       = (float*)d_out;

    const int rows   = in_sizes[0] / FFT_N;              // 65536
    const int pairs  = rows / 2;                         // 32768
    const int blocks = pairs / (WAVES_PER_BLOCK * 2);    // 4096
    hipLaunchKernelGGL(fft512_pack2_kernel, dim3(blocks), dim3(256), 0, stream,
                       x, win, out);
}

// Round 10
// 229.393 us; speedup vs baseline: 1.0061x; 1.0061x over previous
//
#include <hip/hip_runtime.h>
#include <math.h>

#define FFT_N 512
#define LDS_STRIDE 576   // per-block LDS in float2 (4608 B); max addr used = 574

// Zero-instruction fence: orders C++ LDS accesses (memory clobber) and pins
// scheduler motion. The block is ONE wave and owns all its LDS; same-wave DS
// ops complete in order, so write->read needs no hard drain (compiler emits
// counted lgkmcnt before register uses).
#define WAVE_LDS_FENCE() do { \
    asm volatile("" ::: "memory"); \
    __builtin_amdgcn_wave_barrier(); \
    asm volatile("" ::: "memory"); \
} while (0)

// In-register 8-point complex DFT (DIF radix-2^3), outputs in NATURAL order.
__device__ __forceinline__ void fft8(float* re, float* im) {
    const float C = 0.70710678118654752440f;
    float tr[8], ti[8];
    tr[0]=re[0]+re[4]; ti[0]=im[0]+im[4];
    tr[4]=re[0]-re[4]; ti[4]=im[0]-im[4];
    tr[1]=re[1]+re[5]; ti[1]=im[1]+im[5];
    tr[5]=re[1]-re[5]; ti[5]=im[1]-im[5];
    tr[2]=re[2]+re[6]; ti[2]=im[2]+im[6];
    tr[6]=re[2]-re[6]; ti[6]=im[2]-im[6];
    tr[3]=re[3]+re[7]; ti[3]=im[3]+im[7];
    tr[7]=re[3]-re[7]; ti[7]=im[3]-im[7];
    { float a=tr[5], b=ti[5]; tr[5]=C*(a+b); ti[5]=C*(b-a); }
    { float a=tr[6], b=ti[6]; tr[6]=b;       ti[6]=-a;      }
    { float a=tr[7], b=ti[7]; tr[7]=C*(b-a); ti[7]=-C*(a+b);}
    {
        float s0r=tr[0]+tr[2], s0i=ti[0]+ti[2];
        float s2r=tr[0]-tr[2], s2i=ti[0]-ti[2];
        float s1r=tr[1]+tr[3], s1i=ti[1]+ti[3];
        float dr =tr[1]-tr[3], di =ti[1]-ti[3];
        float s3r= di, s3i=-dr;
        re[0]=s0r+s1r; im[0]=s0i+s1i;
        re[2]=s2r+s3r; im[2]=s2i+s3i;
        re[4]=s0r-s1r; im[4]=s0i-s1i;
        re[6]=s2r-s3r; im[6]=s2i-s3i;
    }
    {
        float s0r=tr[4]+tr[6], s0i=ti[4]+ti[6];
        float s2r=tr[4]-tr[6], s2i=ti[4]-ti[6];
        float s1r=tr[5]+tr[7], s1i=ti[5]+ti[7];
        float dr =tr[5]-tr[7], di =ti[5]-ti[7];
        float s3r= di, s3i=-dr;
        re[1]=s0r+s1r; im[1]=s0i+s1i;
        re[3]=s2r+s3r; im[3]=s2i+s3i;
        re[5]=s0r-s1r; im[5]=s0i-s1i;
        re[7]=s2r-s3r; im[7]=s2i-s3i;
    }
}

// Apply tw[k] = base^k (chained complex multiply) to regs 1..7.
__device__ __forceinline__ void twiddle_chain(float* re, float* im,
                                              float c, float s) {
    float cr = c, ci = s;
#pragma unroll
    for (int k = 1; k < 8; ++k) {
        float a = re[k], b = im[k];
        re[k] = a * cr - b * ci;
        im[k] = a * ci + b * cr;
        float ncr = cr * c - ci * s;
        float nci = cr * s + ci * c;
        cr = ncr; ci = nci;
    }
}

// Exchange-3 slot swizzle: A3(k) = 64*(k>>6) + swz3(k&63).
// Injective in m-bits{0,3,4,5} (write via rot3(lane)) and in
// m-bits{2,3,4,5} (both mirrored reads) within every 16-lane phase.
__device__ __forceinline__ int swz3(int m) {
    return ((m ^ (m >> 2)) & 1)
         | (((m >> 3) & 7) << 1)
         | (((m >> 1) & 1) << 4)
         | (((m >> 2) & 1) << 5);
}

// ONE WAVE PER BLOCK: 64-thread blocks, each processing one row-pair.
// Independent blocks have independent dispatch phases -> no intra-block
// convoy alignment of load/LDS/VALU bursts; up to 32 blocks/CU resident.
// z = x[2q] + i*x[2q+1], one 512-pt complex FFT,
// unpack Re(A) = (ReZ[k]+ReZ[N-k])/2, Re(B) = (ImZ[k]+ImZ[N-k])/2.
// Decimation: n = 64*n1 + 8*n2 + n3 ; k = k1 + 8*k2 + 64*k3.
// All LDS exchanges conflict-free under the 16-lane b64 phase model.
__global__ __launch_bounds__(64) void fft512_pack2_kernel(
        const float* __restrict__ x,
        const float* __restrict__ win,
        float* __restrict__ out) {
    __shared__ float2 L[LDS_STRIDE];

    const int lane = threadIdx.x & 63;
    const int pair = blockIdx.x;

    const int t4   = lane << 2;
    const int u    = lane & 15;
    const int pp   = lane >> 4;
    const int x0sw = (lane >> 2) & 3;            // exch-0 write XOR (on j)
    const int l0r  = lane ^ pp;                  // exch-0 read lane index
    const int k1p  = lane >> 3;                  // exch-1 read / exch-2 write role
    const int n3p  = lane & 7;
    const int rl   = (lane >> 3) | ((lane & 7) << 3);  // post-C k&63
    const int s3w  = swz3(rl);                   // exch-3 write slot

    int sm[4], smm[4];
#pragma unroll
    for (int j = 0; j < 4; ++j) {
        const int m = 4 * u + j;
        sm[j]  = swz3(m);
        smm[j] = swz3((64 - m) & 63);
    }

    // Twiddle bases (lane-only).
    float cA, sA, cB, sB;
    __sincosf(-6.283185307179586f * (float)lane * (1.0f / 512.0f), &sA, &cA);
    __sincosf(-6.283185307179586f * (float)n3p  * (1.0f / 64.0f),  &sB, &cB);

    const float* __restrict__ x0 = x + (size_t)(2 * pair) * FFT_N;
    const float* __restrict__ x1 = x0 + FFT_N;

    // ---- Vectorized global loads: 16 B/lane, fully coalesced ----
    const float4 w0  = *(const float4*)(win + t4);
    const float4 w1  = *(const float4*)(win + t4 + 256);
    const float4 xa0 = *(const float4*)(x0 + t4);
    const float4 xb0 = *(const float4*)(x1 + t4);
    const float4 xa1 = *(const float4*)(x0 + t4 + 256);
    const float4 xb1 = *(const float4*)(x1 + t4 + 256);

    // ---- Exchange 0 write: A0(i) = i ^ ((i>>4)&3) = base + (j^x0sw) ----
    {
        const float* a0 = (const float*)&xa0;
        const float* b0 = (const float*)&xb0;
        const float* a1 = (const float*)&xa1;
        const float* b1 = (const float*)&xb1;
        const float* W0 = (const float*)&w0;
        const float* W1 = (const float*)&w1;
#pragma unroll
        for (int j = 0; j < 4; ++j) {
            const int sl = j ^ x0sw;
            L[t4 +       sl] = make_float2(a0[j] * W0[j], b0[j] * W0[j]);
            L[t4 + 256 + sl] = make_float2(a1[j] * W1[j], b1[j] * W1[j]);
        }
    }
    WAVE_LDS_FENCE();

    // ---- Exchange 0 read: element 64*n1 + lane is at 64*n1 + (lane^pp) ----
    float re[8], im[8];
#pragma unroll
    for (int n1 = 0; n1 < 8; ++n1) {
        float2 v = L[n1 * 64 + l0r];
        re[n1] = v.x; im[n1] = v.y;
    }
    WAVE_LDS_FENCE();

    // ---- Stage A: DFT8 over n1 + twiddle W512^{lane*k1} ----
    fft8(re, im);
    twiddle_chain(re, im, cA, sA);

    // ---- Exchange 1: addr = k1*72 + (8*n2 + n3) ----
#pragma unroll
    for (int k1 = 0; k1 < 8; ++k1)
        L[k1 * 72 + lane] = make_float2(re[k1], im[k1]);
    WAVE_LDS_FENCE();
#pragma unroll
    for (int n2 = 0; n2 < 8; ++n2) {
        float2 v = L[k1p * 72 + n2 * 8 + n3p];
        re[n2] = v.x; im[n2] = v.y;
    }
    WAVE_LDS_FENCE();

    // ---- Stage B: DFT8 over n2 + twiddle W64^{n3p*k2} ----
    fft8(re, im);
    twiddle_chain(re, im, cB, sB);

    // ---- Exchange 2: addr = (k1*8 + k2)*9 + n3 ----
#pragma unroll
    for (int k2 = 0; k2 < 8; ++k2)
        L[(k1p * 8 + k2) * 9 + n3p] = make_float2(re[k2], im[k2]);
    WAVE_LDS_FENCE();
    // Read role: k1 = lane>>3, k2 = lane&7  =>  addr = lane*9 + n3.
#pragma unroll
    for (int n3 = 0; n3 < 8; ++n3) {
        float2 v = L[lane * 9 + n3];
        re[n3] = v.x; im[n3] = v.y;
    }
    WAVE_LDS_FENCE();

    // ---- Stage C ----
    fft8(re, im);
    // Thread holds Z[k], k = rl + 64*k3.

    // ---- Exchange 3: Z[k] at 64*(k>>6) + swz3(k&63) ----
#pragma unroll
    for (int k3 = 0; k3 < 8; ++k3)
        L[(k3 << 6) + s3w] = make_float2(re[k3], im[k3]);
    WAVE_LDS_FENCE();

    // ---- Output: float4 stores ----
    float* __restrict__ o0 = out + (size_t)(2 * pair) * FFT_N;
    float* __restrict__ o1 = o0 + FFT_N;
#pragma unroll
    for (int half = 0; half < 2; ++half) {
        const int hk = 4 * half + pp;
        float4 ra, rb;
        float* pa = (float*)&ra;
        float* pb = (float*)&rb;
#pragma unroll
        for (int j = 0; j < 4; ++j) {
            const int m  = 4 * u + j;
            const int hn = ((512 - (hk << 6) - m) >> 6) & 7;
            const float2 zk = L[(hk << 6) + sm[j]];
            const float2 zn = L[(hn << 6) + smm[j]];
            pa[j] = 0.5f * (zk.x + zn.x);
            pb[j] = 0.5f * (zk.y + zn.y);
        }
        *(float4*)(o0 + 256 * half + t4) = ra;
        *(float4*)(o1 + 256 * half + t4) = rb;
    }
}

extern "C" void kernel_launch(void* const* d_in, const int* in_sizes, int n_in,
                              void* d_out, int out_size, void* d_ws, size_t ws_size,
                              hipStream_t stream) {
    const float* x   = (const float*)d_in[0];
    const float* win = (const float*)d_in[1];
    float* out       = (float*)d_out;

    const int rows  = in_sizes[0] / FFT_N;   // 65536
    const int pairs = rows / 2;              // 32768 blocks, 1 wave each
    hipLaunchKernelGGL(fft512_pack2_kernel, dim3(pairs), dim3(64), 0, stream,
                       x, win, out);
}